// Round 12
// baseline (48.624 us; speedup 1.0000x reference)
//
#include <hip/hip_runtime.h>

#define NB 4
#define NN 2048
#define NF 256
#define NK 4
#define ND 64
#define NEG 0.2f
#define LOG2E 1.4426950408889634f

typedef _Float16 f16;
typedef _Float16 f16x2 __attribute__((ext_vector_type(2)));
typedef _Float16 f16x4 __attribute__((ext_vector_type(4)));
typedef _Float16 f16x8 __attribute__((ext_vector_type(8)));
typedef float f32x4 __attribute__((ext_vector_type(4)));
typedef float f32x16 __attribute__((ext_vector_type(16)));
typedef unsigned int u32;
typedef unsigned short u16;

// 3-bit group swizzle for the wht slab layout (k1 store must match k2 read)
__device__ __forceinline__ int gsz(int d) { return (d ^ (d >> 3)) & 7; }

// ---------------------------------------------------------------------------
// K01: merged k1 (GEMM) + k0 (adj bit-pack), INTERLEAVED block order so k0's
// HBM stream starts at t=0 and overlaps k1's compute: bx%9==0 -> k1 block
// (bx/9, 256 total), else k0 block (2048 total).
// k1: Wh^T = (x @ W)^T per (b,k), f16. Global layout: 32 slabs of 8KB per
//   (b,k); slab s covers j in [s*64,s*64+64):
//     elem(d, j) at s*4096 + d*64 + ((g ^ gsz(d))<<3) + (j&7),  g=(j>>3)&7
//   Epilogue: s = Wh a_src -> sbuf(f32); t -> E=exp(t), F=exp(0.2t) as f16.
// k0: abit[b][i][jw] = bits of (adj>0 | I), 64 words/row.
// ---------------------------------------------------------------------------
__global__ __launch_bounds__(256) void k01(
    const float* __restrict__ x,      // (B,N,F)
    const int*   __restrict__ adj,    // (B,N,N)
    const float* __restrict__ Wm,     // (K,F,D)
    const float* __restrict__ a_src,  // (K,D)
    const float* __restrict__ a_dst,  // (K,D)
    unsigned int* __restrict__ abit,  // (B,N,64)
    f16* __restrict__ wht,            // slab layout, see above
    float* __restrict__ sbuf,         // (B,K,N) f32
    f16* __restrict__ ebuf,           // (B,K,N) f16 exp(t)
    f16* __restrict__ fbuf)           // (B,K,N) f16 exp(0.2 t)
{
    __shared__ f16 wt[64 * 256];  // k1 only: W^T, xor-swizzled in f

    const int bx  = blockIdx.x;
    const int tid = threadIdx.x;

    if ((bx % 9) != 0) {
        // ---------------- k0: bit-pack ----------------
        const int k0idx = bx - bx / 9 - 1;            // 0..2047
        const int row = k0idx * 4 + (tid >> 6);       // b*NN + i
        const int l   = tid & 63;
        const int i   = row & (NN - 1);
        const int* __restrict__ ar = adj + (size_t)row * NN;

        int v[32];
#pragma unroll
        for (int c = 0; c < 32; ++c) v[c] = ar[c * 64 + l];

        unsigned int kx = 0, ky = 0;
#pragma unroll
        for (int c = 0; c < 32; ++c) {
            unsigned long long m = __ballot(v[c] > 0);
            if (l == c) { kx = (unsigned int)m; ky = (unsigned int)(m >> 32); }
        }
        if (l == (i >> 6)) {          // self-loop bit
            unsigned int sb = 1u << (i & 31);
            if (((i >> 5) & 1) == 0) kx |= sb; else ky |= sb;
        }
        if (l < 32) {
            uint2 kk; kk.x = kx; kk.y = ky;
            *(uint2*)&abit[(size_t)row * 64 + l * 2] = kk;
        }
        return;
    }

    // ---------------- k1: GEMM ----------------
    const int gemm = bx / 9;      // 0..255
    const int gx  = gemm & 15;    // n-group of 128
    const int k   = (gemm >> 4) & 3;
    const int b   = gemm >> 6;
    const int wv  = tid >> 6;
    const int l   = tid & 63;
    const int q   = l >> 4;
    const int r16 = l & 15;

    for (int fc = 0; fc < 64; ++fc) {
        int f = fc * 4 + wv;
        int d = l;
        wt[d * 256 + (f ^ ((d & 7) << 3))] = (f16)Wm[(k * NF + f) * ND + d];
    }
    __syncthreads();

    const int ncol0 = gx * 128 + wv * 32;
    f32x4 acc[2][4];
#pragma unroll
    for (int nt = 0; nt < 2; ++nt)
#pragma unroll
        for (int dt = 0; dt < 4; ++dt)
            acc[nt][dt] = (f32x4){0.f, 0.f, 0.f, 0.f};

    for (int fs = 0; fs < 16; ++fs) {           // K-steps of 16
        const int f0 = fs * 16 + q * 4;
        f16x4 af[4];
#pragma unroll
        for (int dt = 0; dt < 4; ++dt) {
            int d = dt * 16 + r16;
            af[dt] = *(const f16x4*)&wt[d * 256 + (f0 ^ ((d & 7) << 3))];
        }
#pragma unroll
        for (int nt = 0; nt < 2; ++nt) {
            int n = ncol0 + nt * 16 + r16;
            float4 xv = *(const float4*)&x[((size_t)(b * NN + n)) * NF + f0];
            f16x4 bf = {(f16)xv.x, (f16)xv.y, (f16)xv.z, (f16)xv.w};
#pragma unroll
            for (int dt = 0; dt < 4; ++dt)
                acc[nt][dt] = __builtin_amdgcn_mfma_f32_16x16x16f16(
                    af[dt], bf, acc[nt][dt], 0, 0, 0);
        }
    }

    float asv[4][4], adv[4][4];
#pragma unroll
    for (int dt = 0; dt < 4; ++dt)
#pragma unroll
        for (int rr = 0; rr < 4; ++rr) {
            int d = dt * 16 + q * 4 + rr;
            asv[dt][rr] = a_src[k * ND + d];
            adv[dt][rr] = a_dst[k * ND + d];
        }

    const size_t obase = (size_t)(b * NK + k) * 131072;

#pragma unroll
    for (int nt = 0; nt < 2; ++nt) {
        int n  = ncol0 + nt * 16 + r16;
        int s_ = n >> 6, g = (n >> 3) & 7, e = n & 7;
        float sp = 0.f, tp = 0.f;
#pragma unroll
        for (int dt = 0; dt < 4; ++dt)
#pragma unroll
            for (int rr = 0; rr < 4; ++rr) {
                float v = acc[nt][dt][rr];
                int d = dt * 16 + q * 4 + rr;    // C row = d'
                wht[obase + s_ * 4096 + d * 64 + ((g ^ gsz(d)) << 3) + e] = (f16)v;
                sp += v * asv[dt][rr];
                tp += v * adv[dt][rr];
            }
        sp += __shfl_xor(sp, 16);
        sp += __shfl_xor(sp, 32);
        tp += __shfl_xor(tp, 16);
        tp += __shfl_xor(tp, 32);
        if (q == 0) {
            int idx = (b * NK + k) * NN + n;
            sbuf[idx] = sp;
            ebuf[idx] = (f16)__builtin_exp2f(tp * LOG2E);
            fbuf[idx] = (f16)__builtin_exp2f(0.2f * LOG2E * tp);
        }
    }
}

// ---------------------------------------------------------------------------
// K2 v10 (proven 42.0us config, restored exactly): v8 base + XCD-pinned grid
// + ones-MFMA denominator. Block = 512 thr = 8 waves = 2 row-waves (64 i) x
// 4 j-chunks (512 j). 1D grid 512: bkv=(bid&7)|((bid>>3)&1)<<3 pins each
// (b,k)'s blocks to one XCD -> wht slice L2-resident. Denominator:
// accd = mfma(pa, ones, accd) -> row-sums in regs, same C/D map as acc.
// ---------------------------------------------------------------------------
__global__ __launch_bounds__(512, 4) void k2_attn(
    const unsigned int* __restrict__ abit,  // (B,N,64) bit-mask
    const f16* __restrict__ wht,            // slab layout
    const float* __restrict__ sbuf,         // (B,K,N)
    const f16* __restrict__ ebuf,           // (B,K,N) f16
    const f16* __restrict__ fbuf,           // (B,K,N) f16
    float* __restrict__ out)                // (B,N,K*D)
{
    const int bid = blockIdx.x;
    const int bkv = (bid & 7) | (((bid >> 3) & 1) << 3);  // XCD-pinned (b,k)
    const int rg  = bid >> 4;                             // row-group 0..31
    const int b   = bkv >> 2, k = bkv & 3;
    const int i0  = rg * 64;
    const int tid = threadIdx.x;
    const int w   = tid >> 6;
    const int c   = w >> 1;          // j-chunk 0..3
    const int rw  = w & 1;           // row-wave 0..1
    const int l   = tid & 63;
    const int r32 = l & 31;
    const int hi  = l >> 5;
    const int iglob = i0 + rw * 32 + r32;

    // LDS: [0,64K) stage (chunk c at c*16K, 2 bufs of 8K);
    // [64K,68K) el f16; [68K,72K) fl f16. Stash (epilogue) reuses [0,72K).
    __shared__ __attribute__((aligned(16))) char pool[74752];
    u16* el = (u16*)(pool + 65536);
    u16* fl = (u16*)(pool + 69632);

    // adj bits: 8 iters x 64 bits for this lane's row, this chunk
    const unsigned int* __restrict__ abrow =
        abit + (size_t)(b * NN + iglob) * 64 + c * 16;
    uint2 abx[8];
#pragma unroll
    for (int it = 0; it < 8; ++it) abx[it] = *(const uint2*)(abrow + it * 2);

    {   // stage E/F as f16 (4KB each), coalesced, once
        const u16* eb = (const u16*)(ebuf + bkv * NN);
        const u16* fb = (const u16*)(fbuf + bkv * NN);
        *(ushort4*)&el[tid * 4] = *(const ushort4*)&eb[tid * 4];
        *(ushort4*)&fl[tid * 4] = *(const ushort4*)&fb[tid * 4];
    }

    const float s   = sbuf[bkv * NN + iglob];
    const f16 Afh = (f16)__builtin_exp2f(0.8f * LOG2E * fminf(s, 0.f));   // <=1
    const f16 Bfh = (f16)__builtin_exp2f(-0.8f * LOG2E * fmaxf(s, 0.f));  // <=1
    const f16x2 Af2 = {Afh, Afh};
    const f16x2 Bf2 = {Bfh, Bfh};
    const f16 h1 = (f16)1.0f;
    const f16x8 ones8 = {h1, h1, h1, h1, h1, h1, h1, h1};
    const char* gtiles = (const char*)wht + (size_t)bkv * 262144;

    f32x16 acc[2], accd;
#pragma unroll
    for (int z = 0; z < 16; ++z) { acc[0][z] = 0.f; acc[1][z] = 0.f; accd[z] = 0.f; }

#define STAGE8(bb, it)                                                         \
    do {                                                                       \
        const char* gsrc = gtiles + (size_t)(c * 8 + (it)) * 8192 +            \
                           rw * 1024 + l * 16;                                 \
        char* ldst = pool + c * 16384 + (bb) * 8192 + rw * 1024 + l * 16;      \
        _Pragma("unroll") for (int kk = 0; kk < 4; ++kk)                       \
            __builtin_amdgcn_global_load_lds(                                  \
                (const __attribute__((address_space(1))) void*)(gsrc +         \
                    kk * 2048),                                                \
                (__attribute__((address_space(3))) void*)(ldst + kk * 2048),   \
                16, 0, 0);                                                     \
    } while (0)

    STAGE8(0, 0);

#pragma unroll
    for (int it = 0; it < 8; ++it) {
        // drain stage(it) (and, at it=0, all prologue loads + E/F ds_writes)
        asm volatile("s_waitcnt vmcnt(0) lgkmcnt(0)" ::: "memory");
        __builtin_amdgcn_sched_barrier(0);
        __builtin_amdgcn_s_barrier();
        __builtin_amdgcn_sched_barrier(0);
        if (it < 7) STAGE8((it + 1) & 1, it + 1);  // buf freed by compute(it-1)

        const char* lb = pool + c * 16384 + (it & 1) * 8192;
        const uint2 ab = abx[it];
#pragma unroll
        for (int jts = 0; jts < 4; ++jts) {
            const u32 word = (jts & 2) ? ab.y : ab.x;
            const u32 bbyte = (word >> (((jts & 1) << 4) + (hi << 3))) & 0xffu;
            const u32 u = (bbyte << 15) | bbyte;     // byte | byte<<15
            const int jb = c * 512 + it * 64 + jts * 16 + hi * 8;
            uint4 E4 = *(const uint4*)&el[jb];
            uint4 F4 = *(const uint4*)&fl[jb];
            u32 pa_u[4];
#pragma unroll
            for (int p = 0; p < 4; ++p) {
                f16x2 e2 = __builtin_bit_cast(f16x2, ((const u32*)&E4)[p]);
                f16x2 f2 = __builtin_bit_cast(f16x2, ((const u32*)&F4)[p]);
                f16x2 w2 = __builtin_elementwise_max(Af2 * e2, Bf2 * f2);
                u32 x  = (u >> (2 * p)) & 0x00010001u;   // {bit2p+1, bit2p}
                u32 mm = (x << 16) - x;                  // FFFF/0000 halves
                pa_u[p] = __builtin_bit_cast(u32, w2) & mm;
            }
            uint4 pav = {pa_u[0], pa_u[1], pa_u[2], pa_u[3]};
            f16x8 pa = __builtin_bit_cast(f16x8, pav);
#pragma unroll
            for (int dh = 0; dh < 2; ++dh) {
                const int d = dh * 32 + r32;
                f16x8 v8 = *(const f16x8*)(lb + d * 128 +
                               ((((jts << 1) | hi) ^ gsz(d)) << 4));
                acc[dh] = __builtin_amdgcn_mfma_f32_32x32x16_f16(
                    pa, v8, acc[dh], 0, 0, 0);
            }
            // denominator: row-sum of pa into accd (same reg<->row map as acc)
            accd = __builtin_amdgcn_mfma_f32_32x32x16_f16(pa, ones8, accd, 0, 0, 0);
        }
    }
#undef STAGE8

    __syncthreads();                 // all compute done; stage+E/F reusable
    float* stash = (float*)pool;     // chunks 1..3: [(c-1)*2+rw] x 48 f32/lane
    if (c != 0) {
        float* sb = stash + ((c - 1) * 2 + rw) * 3072 + l * 48;
#pragma unroll
        for (int dh = 0; dh < 2; ++dh)
#pragma unroll
            for (int sub = 0; sub < 4; ++sub) {
                f32x4 v = {acc[dh][sub * 4], acc[dh][sub * 4 + 1],
                           acc[dh][sub * 4 + 2], acc[dh][sub * 4 + 3]};
                *(f32x4*)&sb[dh * 16 + ((sub ^ (l & 3)) << 2)] = v;
            }
#pragma unroll
        for (int sub = 0; sub < 4; ++sub) {
            f32x4 v = {accd[sub * 4], accd[sub * 4 + 1],
                       accd[sub * 4 + 2], accd[sub * 4 + 3]};
            *(f32x4*)&sb[32 + ((sub ^ (l & 3)) << 2)] = v;
        }
    }
    __syncthreads();

    if (c == 0) {
#pragma unroll
        for (int cc = 0; cc < 3; ++cc) {
            const float* sr = stash + (cc * 2 + rw) * 3072 + l * 48;
#pragma unroll
            for (int dh = 0; dh < 2; ++dh)
#pragma unroll
                for (int sub = 0; sub < 4; ++sub) {
                    f32x4 v = *(const f32x4*)&sr[dh * 16 + ((sub ^ (l & 3)) << 2)];
#pragma unroll
                    for (int m = 0; m < 4; ++m) acc[dh][sub * 4 + m] += v[m];
                }
#pragma unroll
            for (int sub = 0; sub < 4; ++sub) {
                f32x4 v = *(const f32x4*)&sr[32 + ((sub ^ (l & 3)) << 2)];
#pragma unroll
                for (int m = 0; m < 4; ++m) accd[sub * 4 + m] += v[m];
            }
        }
        float* op = out + ((size_t)(b * NN) + i0 + rw * 32) * (NK * ND) + k * ND;
#pragma unroll
        for (int g4 = 0; g4 < 4; ++g4)
#pragma unroll
            for (int m = 0; m < 4; ++m) {
                const int rr   = g4 * 4 + m;
                const int irow = g4 * 8 + hi * 4 + m;   // C/D row map (m74/m101)
                const float inv = 1.f / (accd[rr] + 1e-10f);
                op[(size_t)irow * (NK * ND) + r32]      = acc[0][rr] * inv;
                op[(size_t)irow * (NK * ND) + 32 + r32] = acc[1][rr] * inv;
            }
    }
}

extern "C" void kernel_launch(void* const* d_in, const int* in_sizes, int n_in,
                              void* d_out, int out_size, void* d_ws, size_t ws_size,
                              hipStream_t stream) {
    const float* x     = (const float*)d_in[0];
    const int*   adj   = (const int*)d_in[1];
    const float* Wm    = (const float*)d_in[2];
    const float* a_src = (const float*)d_in[3];
    const float* a_dst = (const float*)d_in[4];
    float* out = (float*)d_out;

    char* ws = (char*)d_ws;
    f16*   wht  = (f16*)ws;                                   // 4 MiB
    float* sbuf = (float*)(ws + (4u << 20));                  // 128 KiB
    f16*   ebuf = (f16*)(ws + (4u << 20) + (128u << 10));     // 64 KiB
    f16*   fbuf = (f16*)(ws + (4u << 20) + (192u << 10));     // 64 KiB
    unsigned int* abit = (unsigned int*)(ws + (4u << 20) + (256u << 10)); // 2 MiB

    k01<<<dim3(256 + NB * NN / 4), 256, 0, stream>>>(
        x, adj, Wm, a_src, a_dst, abit, wht, sbuf, ebuf, fbuf);
    k2_attn<<<dim3(512), 512, 0, stream>>>(
        abit, wht, sbuf, ebuf, fbuf, out);
}

// Round 13
// 41.638 us; speedup vs baseline: 1.1678x; 1.1678x over previous
//
#include <hip/hip_runtime.h>

#define NB 4
#define NN 2048
#define NF 256
#define NK 4
#define ND 64
#define NEG 0.2f
#define LOG2E 1.4426950408889634f

typedef _Float16 f16;
typedef _Float16 f16x2 __attribute__((ext_vector_type(2)));
typedef _Float16 f16x4 __attribute__((ext_vector_type(4)));
typedef _Float16 f16x8 __attribute__((ext_vector_type(8)));
typedef float f32x4 __attribute__((ext_vector_type(4)));
typedef float f32x16 __attribute__((ext_vector_type(16)));
typedef unsigned int u32;
typedef unsigned short u16;

// ---------------------------------------------------------------------------
// K01: merged k1 (GEMM, blocks 0..255) + k0 (adj bit-pack, blocks 256..2303).
// (contiguous ordering — R12 proved interleaving regresses.)
// k1: Wh^T = (x @ W)^T per (b,k), f16, OCTET-MAJOR layout:
//     elem(d, j) at wht[(b*NK+k)*131072 + (j>>3)*512 + d*8 + (j&7)]
//   i.e. 256 slabs of 1KB per (b,k); a k2 wave's fragment load (d=r32 lanes,
//   8 consecutive j) is two 512B contiguous L2 segments — no LDS needed.
//   Epilogue: s = Wh a_src -> sbuf(f32); t -> E=exp(t), F=exp(0.2t) as f16.
// k0: abit[b][i][jw] = bits of (adj>0 | I), 64 words/row.
// ---------------------------------------------------------------------------
__global__ __launch_bounds__(256) void k01(
    const float* __restrict__ x,      // (B,N,F)
    const int*   __restrict__ adj,    // (B,N,N)
    const float* __restrict__ Wm,     // (K,F,D)
    const float* __restrict__ a_src,  // (K,D)
    const float* __restrict__ a_dst,  // (K,D)
    unsigned int* __restrict__ abit,  // (B,N,64)
    f16* __restrict__ wht,            // octet-major, see above
    float* __restrict__ sbuf,         // (B,K,N) f32
    f16* __restrict__ ebuf,           // (B,K,N) f16 exp(t)
    f16* __restrict__ fbuf)           // (B,K,N) f16 exp(0.2 t)
{
    __shared__ f16 wt[64 * 256];  // k1 only: W^T, xor-swizzled in f

    const int bx  = blockIdx.x;
    const int tid = threadIdx.x;

    if (bx >= 256) {
        // ---------------- k0: bit-pack ----------------
        const int row = (bx - 256) * 4 + (tid >> 6);  // b*NN + i
        const int l   = tid & 63;
        const int i   = row & (NN - 1);
        const int* __restrict__ ar = adj + (size_t)row * NN;

        int v[32];
#pragma unroll
        for (int c = 0; c < 32; ++c) v[c] = ar[c * 64 + l];

        unsigned int kx = 0, ky = 0;
#pragma unroll
        for (int c = 0; c < 32; ++c) {
            unsigned long long m = __ballot(v[c] > 0);
            if (l == c) { kx = (unsigned int)m; ky = (unsigned int)(m >> 32); }
        }
        if (l == (i >> 6)) {          // self-loop bit
            unsigned int sb = 1u << (i & 31);
            if (((i >> 5) & 1) == 0) kx |= sb; else ky |= sb;
        }
        if (l < 32) {
            uint2 kk; kk.x = kx; kk.y = ky;
            *(uint2*)&abit[(size_t)row * 64 + l * 2] = kk;
        }
        return;
    }

    // ---------------- k1: GEMM ----------------
    const int gx  = bx & 15;      // n-group of 128
    const int k   = (bx >> 4) & 3;
    const int b   = bx >> 6;
    const int wv  = tid >> 6;
    const int l   = tid & 63;
    const int q   = l >> 4;
    const int r16 = l & 15;

    for (int fc = 0; fc < 64; ++fc) {
        int f = fc * 4 + wv;
        int d = l;
        wt[d * 256 + (f ^ ((d & 7) << 3))] = (f16)Wm[(k * NF + f) * ND + d];
    }
    __syncthreads();

    const int ncol0 = gx * 128 + wv * 32;
    f32x4 acc[2][4];
#pragma unroll
    for (int nt = 0; nt < 2; ++nt)
#pragma unroll
        for (int dt = 0; dt < 4; ++dt)
            acc[nt][dt] = (f32x4){0.f, 0.f, 0.f, 0.f};

    for (int fs = 0; fs < 16; ++fs) {           // K-steps of 16
        const int f0 = fs * 16 + q * 4;
        f16x4 af[4];
#pragma unroll
        for (int dt = 0; dt < 4; ++dt) {
            int d = dt * 16 + r16;
            af[dt] = *(const f16x4*)&wt[d * 256 + (f0 ^ ((d & 7) << 3))];
        }
#pragma unroll
        for (int nt = 0; nt < 2; ++nt) {
            int n = ncol0 + nt * 16 + r16;
            float4 xv = *(const float4*)&x[((size_t)(b * NN + n)) * NF + f0];
            f16x4 bf = {(f16)xv.x, (f16)xv.y, (f16)xv.z, (f16)xv.w};
#pragma unroll
            for (int dt = 0; dt < 4; ++dt)
                acc[nt][dt] = __builtin_amdgcn_mfma_f32_16x16x16f16(
                    af[dt], bf, acc[nt][dt], 0, 0, 0);
        }
    }

    float asv[4][4], adv[4][4];
#pragma unroll
    for (int dt = 0; dt < 4; ++dt)
#pragma unroll
        for (int rr = 0; rr < 4; ++rr) {
            int d = dt * 16 + q * 4 + rr;
            asv[dt][rr] = a_src[k * ND + d];
            adv[dt][rr] = a_dst[k * ND + d];
        }

    const size_t obase = (size_t)(b * NK + k) * 131072;

#pragma unroll
    for (int nt = 0; nt < 2; ++nt) {
        int n  = ncol0 + nt * 16 + r16;
        const size_t sb_ = obase + (size_t)(n >> 3) * 512 + (n & 7);
        float sp = 0.f, tp = 0.f;
#pragma unroll
        for (int dt = 0; dt < 4; ++dt)
#pragma unroll
            for (int rr = 0; rr < 4; ++rr) {
                float v = acc[nt][dt][rr];
                int d = dt * 16 + q * 4 + rr;    // C row = d'
                wht[sb_ + d * 8] = (f16)v;
                sp += v * asv[dt][rr];
                tp += v * adv[dt][rr];
            }
        sp += __shfl_xor(sp, 16);
        sp += __shfl_xor(sp, 32);
        tp += __shfl_xor(tp, 16);
        tp += __shfl_xor(tp, 32);
        if (q == 0) {
            int idx = (b * NK + k) * NN + n;
            sbuf[idx] = sp;
            ebuf[idx] = (f16)__builtin_exp2f(tp * LOG2E);
            fbuf[idx] = (f16)__builtin_exp2f(0.2f * LOG2E * tp);
        }
    }
}

// ---------------------------------------------------------------------------
// K2 v12: DIRECT-GLOBAL fragments — no staging, no intra-loop barriers.
// Block = 512 thr = 8 waves = 2 row-waves (64 i) x 4 j-chunks (512 j).
// 1D grid 512, XCD-pinned bkv -> the (b,k) wht slice (256KB) is L2-resident;
// each lane's f16x8 B-fragment is loaded straight from global (a wave load =
// two contiguous 512B L2 segments, octet-major layout). E/F stay in LDS
// (broadcast reads). Waves free-run; compiler pipelines the loads.
// Denominator: accd = mfma(pa, ones, accd) (same C/D reg<->row map as acc).
// ---------------------------------------------------------------------------
__global__ __launch_bounds__(512, 4) void k2_attn(
    const unsigned int* __restrict__ abit,  // (B,N,64) bit-mask
    const f16* __restrict__ wht,            // octet-major
    const float* __restrict__ sbuf,         // (B,K,N)
    const f16* __restrict__ ebuf,           // (B,K,N) f16
    const f16* __restrict__ fbuf,           // (B,K,N) f16
    float* __restrict__ out)                // (B,N,K*D)
{
    const int bid = blockIdx.x;
    const int bkv = (bid & 7) | (((bid >> 3) & 1) << 3);  // XCD-pinned (b,k)
    const int rg  = bid >> 4;                             // row-group 0..31
    const int b   = bkv >> 2, k = bkv & 3;
    const int i0  = rg * 64;
    const int tid = threadIdx.x;
    const int w   = tid >> 6;
    const int c   = w >> 1;          // j-chunk 0..3
    const int rw  = w & 1;           // row-wave 0..1
    const int l   = tid & 63;
    const int r32 = l & 31;
    const int hi  = l >> 5;
    const int iglob = i0 + rw * 32 + r32;

    // LDS: [0,72K) epilogue stash; [64K,68K) el f16; [68K,72K) fl f16.
    // (el/fl live in the tail; stash only used after compute completes.)
    __shared__ __attribute__((aligned(16))) char pool[74752];
    u16* el = (u16*)(pool + 65536);
    u16* fl = (u16*)(pool + 69632);

    // adj bits: 8 iters x 64 bits for this lane's row, this chunk
    const unsigned int* __restrict__ abrow =
        abit + (size_t)(b * NN + iglob) * 64 + c * 16;
    uint2 abx[8];
#pragma unroll
    for (int it = 0; it < 8; ++it) abx[it] = *(const uint2*)(abrow + it * 2);

    {   // stage E/F as f16 (4KB each), coalesced, once
        const u16* eb = (const u16*)(ebuf + bkv * NN);
        const u16* fb = (const u16*)(fbuf + bkv * NN);
        *(ushort4*)&el[tid * 4] = *(const ushort4*)&eb[tid * 4];
        *(ushort4*)&fl[tid * 4] = *(const ushort4*)&fb[tid * 4];
    }

    const float s   = sbuf[bkv * NN + iglob];
    const f16 Afh = (f16)__builtin_exp2f(0.8f * LOG2E * fminf(s, 0.f));   // <=1
    const f16 Bfh = (f16)__builtin_exp2f(-0.8f * LOG2E * fmaxf(s, 0.f));  // <=1
    const f16x2 Af2 = {Afh, Afh};
    const f16x2 Bf2 = {Bfh, Bfh};
    const f16 h1 = (f16)1.0f;
    const f16x8 ones8 = {h1, h1, h1, h1, h1, h1, h1, h1};

    // lane-constant fragment base: octet s = c*64 + it*8 + jts*2 + hi
    const f16* __restrict__ lanep =
        wht + (size_t)bkv * 131072 + (size_t)(c * 64 + hi) * 512 + r32 * 8;

    f32x16 acc[2], accd;
#pragma unroll
    for (int z = 0; z < 16; ++z) { acc[0][z] = 0.f; acc[1][z] = 0.f; accd[z] = 0.f; }

    // el/fl must be visible to all waves before the loop
    __syncthreads();

#pragma unroll
    for (int it = 0; it < 8; ++it) {
        const uint2 ab = abx[it];
#pragma unroll
        for (int jts = 0; jts < 4; ++jts) {
            const u32 word = (jts & 2) ? ab.y : ab.x;
            const u32 bbyte = (word >> (((jts & 1) << 4) + (hi << 3))) & 0xffu;
            const u32 u = (bbyte << 15) | bbyte;     // byte | byte<<15
            const int jb = c * 512 + it * 64 + jts * 16 + hi * 8;
            uint4 E4 = *(const uint4*)&el[jb];       // broadcast (32 lanes same)
            uint4 F4 = *(const uint4*)&fl[jb];
            u32 pa_u[4];
#pragma unroll
            for (int p = 0; p < 4; ++p) {
                f16x2 e2 = __builtin_bit_cast(f16x2, ((const u32*)&E4)[p]);
                f16x2 f2 = __builtin_bit_cast(f16x2, ((const u32*)&F4)[p]);
                f16x2 w2 = __builtin_elementwise_max(Af2 * e2, Bf2 * f2);
                u32 x  = (u >> (2 * p)) & 0x00010001u;   // {bit2p+1, bit2p}
                u32 mm = (x << 16) - x;                  // FFFF/0000 halves
                pa_u[p] = __builtin_bit_cast(u32, w2) & mm;
            }
            uint4 pav = {pa_u[0], pa_u[1], pa_u[2], pa_u[3]};
            f16x8 pa = __builtin_bit_cast(f16x8, pav);

            // direct-global fragments: octet (it*8 + jts*2 + hi), d = dh*32+r32
            const f16* fp = lanep + (size_t)(it * 8 + jts * 2) * 512;
            f16x8 v80 = *(const f16x8*)(fp);         // dh=0
            f16x8 v81 = *(const f16x8*)(fp + 256);   // dh=1
            acc[0] = __builtin_amdgcn_mfma_f32_32x32x16_f16(pa, v80, acc[0], 0, 0, 0);
            acc[1] = __builtin_amdgcn_mfma_f32_32x32x16_f16(pa, v81, acc[1], 0, 0, 0);
            accd   = __builtin_amdgcn_mfma_f32_32x32x16_f16(pa, ones8, accd, 0, 0, 0);
        }
    }

    __syncthreads();                 // all compute done; pool reusable
    float* stash = (float*)pool;     // chunks 1..3: [(c-1)*2+rw] x 48 f32/lane
    if (c != 0) {
        float* sb = stash + ((c - 1) * 2 + rw) * 3072 + l * 48;
#pragma unroll
        for (int dh = 0; dh < 2; ++dh)
#pragma unroll
            for (int sub = 0; sub < 4; ++sub) {
                f32x4 v = {acc[dh][sub * 4], acc[dh][sub * 4 + 1],
                           acc[dh][sub * 4 + 2], acc[dh][sub * 4 + 3]};
                *(f32x4*)&sb[dh * 16 + ((sub ^ (l & 3)) << 2)] = v;
            }
#pragma unroll
        for (int sub = 0; sub < 4; ++sub) {
            f32x4 v = {accd[sub * 4], accd[sub * 4 + 1],
                       accd[sub * 4 + 2], accd[sub * 4 + 3]};
            *(f32x4*)&sb[32 + ((sub ^ (l & 3)) << 2)] = v;
        }
    }
    __syncthreads();

    if (c == 0) {
#pragma unroll
        for (int cc = 0; cc < 3; ++cc) {
            const float* sr = stash + (cc * 2 + rw) * 3072 + l * 48;
#pragma unroll
            for (int dh = 0; dh < 2; ++dh)
#pragma unroll
                for (int sub = 0; sub < 4; ++sub) {
                    f32x4 v = *(const f32x4*)&sr[dh * 16 + ((sub ^ (l & 3)) << 2)];
#pragma unroll
                    for (int m = 0; m < 4; ++m) acc[dh][sub * 4 + m] += v[m];
                }
#pragma unroll
            for (int sub = 0; sub < 4; ++sub) {
                f32x4 v = *(const f32x4*)&sr[32 + ((sub ^ (l & 3)) << 2)];
#pragma unroll
                for (int m = 0; m < 4; ++m) accd[sub * 4 + m] += v[m];
            }
        }
        float* op = out + ((size_t)(b * NN) + i0 + rw * 32) * (NK * ND) + k * ND;
#pragma unroll
        for (int g4 = 0; g4 < 4; ++g4)
#pragma unroll
            for (int m = 0; m < 4; ++m) {
                const int rr   = g4 * 4 + m;
                const int irow = g4 * 8 + hi * 4 + m;   // C/D row map (m74/m101)
                const float inv = 1.f / (accd[rr] + 1e-10f);
                op[(size_t)irow * (NK * ND) + r32]      = acc[0][rr] * inv;
                op[(size_t)irow * (NK * ND) + 32 + r32] = acc[1][rr] * inv;
            }
    }
}

extern "C" void kernel_launch(void* const* d_in, const int* in_sizes, int n_in,
                              void* d_out, int out_size, void* d_ws, size_t ws_size,
                              hipStream_t stream) {
    const float* x     = (const float*)d_in[0];
    const int*   adj   = (const int*)d_in[1];
    const float* Wm    = (const float*)d_in[2];
    const float* a_src = (const float*)d_in[3];
    const float* a_dst = (const float*)d_in[4];
    float* out = (float*)d_out;

    char* ws = (char*)d_ws;
    f16*   wht  = (f16*)ws;                                   // 4 MiB
    float* sbuf = (float*)(ws + (4u << 20));                  // 128 KiB
    f16*   ebuf = (f16*)(ws + (4u << 20) + (128u << 10));     // 64 KiB
    f16*   fbuf = (f16*)(ws + (4u << 20) + (192u << 10));     // 64 KiB
    unsigned int* abit = (unsigned int*)(ws + (4u << 20) + (256u << 10)); // 2 MiB

    k01<<<dim3(256 + NB * NN / 4), 256, 0, stream>>>(
        x, adj, Wm, a_src, a_dst, abit, wht, sbuf, ebuf, fbuf);
    k2_attn<<<dim3(512), 512, 0, stream>>>(
        abit, wht, sbuf, ebuf, fbuf, out);
}